// Round 1
// baseline (870.105 us; speedup 1.0000x reference)
//
#include <hip/hip_runtime.h>
#include <hip/hip_bf16.h>
#include <stdint.h>

#define NN     30000
#define MPAD   30080          // 235 * 128
#define RR     8
#define NBASES 30
#define KD     256
#define EE     480000
#define NSEG   (NN * RR)

typedef unsigned short u16;
typedef __attribute__((ext_vector_type(8))) short bf16x8;   // 8 bf16 = 4 VGPRs
typedef __attribute__((ext_vector_type(4))) float f32x4;

__device__ __forceinline__ u16 f2b(float f) {
  union { float f; uint32_t u; } v; v.f = f;
  return (u16)((v.u + 0x7fffu + ((v.u >> 16) & 1u)) >> 16);   // RNE
}
__device__ __forceinline__ float b2f(u16 h) {
  union { uint32_t u; float f; } v; v.u = ((uint32_t)h) << 16;
  return v.f;
}

__device__ __forceinline__ void gl_lds16(const void* g, void* l) {
  __builtin_amdgcn_global_load_lds((__attribute__((address_space(1))) void*)g,
                                   (__attribute__((address_space(3))) void*)l,
                                   16, 0, 0);
}

// ---------------- bf16 MFMA GEMM: C[M x NC] = A[M x 256] * BT[NC x 256]^T ---
// cols < split  -> Cb (bf16, row width = split)
// cols >= split -> Cf (f32, row width = wf) + bias
__global__ void k_gemm(const u16* __restrict__ A, const u16* __restrict__ BT,
                       u16* __restrict__ Cb, float* __restrict__ Cf,
                       const float* __restrict__ bias, int split, int wf) {
  __shared__ u16 Alds[128 * 32];
  __shared__ u16 Blds[128 * 32];
  const int tid = threadIdx.x;
  const int w = tid >> 6, lane = tid & 63;
  const int bn = blockIdx.x * 128, bm = blockIdx.y * 128;
  const int wm = (w >> 1) * 64, wn = (w & 1) * 64;
  const int l15 = lane & 15, l4 = lane >> 4;

  f32x4 zero4 = {0.f, 0.f, 0.f, 0.f};
  f32x4 acc[4][4];
  #pragma unroll
  for (int mi = 0; mi < 4; ++mi)
    #pragma unroll
    for (int ni = 0; ni < 4; ++ni) acc[mi][ni] = zero4;

  for (int k0 = 0; k0 < KD; k0 += 32) {
    // stage 128x32 bf16 tiles of A and BT into LDS (wave-uniform base + lane*16)
    #pragma unroll
    for (int it = 0; it < 2; ++it) {
      int chb = it * 256 + w * 64;     // wave-uniform chunk base
      int ch = chb + lane;             // per-lane chunk (16B each)
      int row = ch >> 2, kq = (ch & 3) * 8;
      gl_lds16(&A[(size_t)(bm + row) * KD + k0 + kq], &Alds[(size_t)chb * 8]);
      gl_lds16(&BT[(size_t)(bn + row) * KD + k0 + kq], &Blds[(size_t)chb * 8]);
    }
    __syncthreads();
    bf16x8 av[4], bv[4];
    #pragma unroll
    for (int i = 0; i < 4; ++i) {
      av[i] = *(const bf16x8*)&Alds[(wm + i * 16 + l15) * 32 + l4 * 8];
      bv[i] = *(const bf16x8*)&Blds[(wn + i * 16 + l15) * 32 + l4 * 8];
    }
    #pragma unroll
    for (int mi = 0; mi < 4; ++mi)
      #pragma unroll
      for (int ni = 0; ni < 4; ++ni)
        acc[mi][ni] = __builtin_amdgcn_mfma_f32_16x16x32_bf16(av[mi], bv[ni], acc[mi][ni], 0, 0, 0);
    __syncthreads();
  }

  // epilogue: C/D layout col=lane&15, row=(lane>>4)*4+reg
  #pragma unroll
  for (int mi = 0; mi < 4; ++mi) {
    #pragma unroll
    for (int ni = 0; ni < 4; ++ni) {
      int col = bn + wn + ni * 16 + l15;
      #pragma unroll
      for (int v = 0; v < 4; ++v) {
        int row = bm + wm + mi * 16 + l4 * 4 + v;
        if (row < NN) {
          float val = acc[mi][ni][v];
          if (col < split) Cb[(size_t)row * split + col] = f2b(val);
          else             Cf[(size_t)row * wf + (col - split)] = val + bias[col - split];
        }
      }
    }
  }
}

// ---------------- small kernels ---------------------------------------------
__global__ void k_cast_x(const float* __restrict__ x, u16* __restrict__ xb) {
  int t = blockIdx.x * 256 + threadIdx.x;
  if (t < NN * KD / 4) {
    float4 v = ((const float4*)x)[t];
    union { u16 h[4]; uint2 u; } p;
    p.h[0] = f2b(v.x); p.h[1] = f2b(v.y); p.h[2] = f2b(v.z); p.h[3] = f2b(v.w);
    ((uint2*)xb)[t] = p.u;
  }
}

__global__ void k_combine1(const float* __restrict__ bases, const float* __restrict__ comp,
                           const float* __restrict__ root, u16* __restrict__ WT) {
  int t = blockIdx.x * 256 + threadIdx.x;          // 2304 blocks
  if (t < RR * 256 * 256) {
    int r = t >> 16, i = (t >> 8) & 255, o = t & 255;
    float acc = 0.f;
    #pragma unroll
    for (int b = 0; b < NBASES; ++b)
      acc += comp[r * NBASES + b] * bases[((size_t)b * 256 + i) * 256 + o];
    WT[((size_t)(r * 256 + o)) * KD + i] = f2b(acc);
  } else {
    int u = t - RR * 256 * 256;
    int i = u >> 8, o = u & 255;
    WT[((size_t)(2048 + o)) * KD + i] = f2b(root[i * 256 + o]);
  }
}

__global__ void k_combine2(const float* __restrict__ bases, const float* __restrict__ comp,
                           const float* __restrict__ root, u16* __restrict__ WT) {
  int t = blockIdx.x * 256 + threadIdx.x;          // 1152 blocks
  if (t < RR * 256 * 128) {
    int r = t >> 15, i = (t >> 7) & 255, o = t & 127;
    float acc = 0.f;
    #pragma unroll
    for (int b = 0; b < NBASES; ++b)
      acc += comp[r * NBASES + b] * bases[((size_t)b * 256 + i) * 128 + o];
    WT[((size_t)(r * 128 + o)) * KD + i] = f2b(acc);
  } else {
    int u = t - RR * 256 * 128;
    int i = u >> 7, o = u & 127;
    WT[((size_t)(1024 + o)) * KD + i] = f2b(root[i * 128 + o]);
  }
}

__global__ void k_hist(const int* __restrict__ ei, const int* __restrict__ ety,
                       int* __restrict__ cnt) {
  int e = blockIdx.x * 256 + threadIdx.x;
  if (e < EE) atomicAdd(&cnt[ei[EE + e] * RR + ety[e]], 1);
}

__global__ void k_inv(const int* __restrict__ cnt, float* __restrict__ inv) {
  int s = blockIdx.x * 256 + threadIdx.x;
  if (s < NSEG) { int c = cnt[s]; inv[s] = c > 0 ? 1.0f / (float)c : 0.f; }
}

// per-edge: out[dst, c] += xall[src, etype, c] * inv_cnt[dst, etype]
__global__ void k_scatter(const u16* __restrict__ xall, const int* __restrict__ ei,
                          const int* __restrict__ ety, const float* __restrict__ inv,
                          float* __restrict__ out, int logC) {
  int C = 1 << logC;
  int e = blockIdx.x * (256 >> logC) + (threadIdx.x >> logC);
  int c = threadIdx.x & (C - 1);
  if (e < EE) {
    int s = ei[e], d = ei[EE + e], r = ety[e];
    float w = inv[d * RR + r];
    float v = b2f(xall[(size_t)s * (RR << logC) + (r << logC) + c]) * w;
    atomicAdd(&out[(size_t)d * C + c], v);
  }
}

__global__ void k_act(const float* __restrict__ z, u16* __restrict__ zb) {
  int t = blockIdx.x * 256 + threadIdx.x;
  if (t < NN * KD / 4) {
    float4 v = ((const float4*)z)[t];
    v.x = v.x > 0.f ? v.x : 0.01f * v.x;
    v.y = v.y > 0.f ? v.y : 0.01f * v.y;
    v.z = v.z > 0.f ? v.z : 0.01f * v.z;
    v.w = v.w > 0.f ? v.w : 0.01f * v.w;
    union { u16 h[4]; uint2 u; } p;
    p.h[0] = f2b(v.x); p.h[1] = f2b(v.y); p.h[2] = f2b(v.z); p.h[3] = f2b(v.w);
    ((uint2*)zb)[t] = p.u;
  }
}

// ---------------- launch ----------------------------------------------------
extern "C" void kernel_launch(void* const* d_in, const int* in_sizes, int n_in,
                              void* d_out, int out_size, void* d_ws, size_t ws_size,
                              hipStream_t stream) {
  const float* x      = (const float*)d_in[0];
  const int*   ei     = (const int*)d_in[1];
  const int*   ety    = (const int*)d_in[2];
  const float* bases1 = (const float*)d_in[3];
  const float* comp1  = (const float*)d_in[4];
  const float* root1  = (const float*)d_in[5];
  const float* bias1  = (const float*)d_in[6];
  const float* bases2 = (const float*)d_in[7];
  const float* comp2  = (const float*)d_in[8];
  const float* root2  = (const float*)d_in[9];
  const float* bias2  = (const float*)d_in[10];
  float* out = (float*)d_out;

  char* p = (char*)d_ws;
  auto alloc = [&](size_t bytes) {
    char* q = p; p += (bytes + 255) & ~(size_t)255; return q;
  };
  u16*   xb   = (u16*)alloc((size_t)MPAD * KD * 2);
  u16*   WT1  = (u16*)alloc((size_t)2304 * KD * 2);
  u16*   xall = (u16*)alloc((size_t)MPAD * 2048 * 2);  // reused as zall2
  float* z1   = (float*)alloc((size_t)NN * 256 * 4);
  u16*   z1b  = (u16*)alloc((size_t)MPAD * KD * 2);
  u16*   WT2  = (u16*)alloc((size_t)1152 * KD * 2);
  int*   cnt  = (int*)alloc((size_t)NSEG * 4);
  float* inv  = (float*)alloc((size_t)NSEG * 4);
  u16*   zall2 = xall;

  hipMemsetAsync(cnt, 0, (size_t)NSEG * 4, stream);
  k_hist<<<(EE + 255) / 256, 256, 0, stream>>>(ei, ety, cnt);
  k_inv<<<(NSEG + 255) / 256, 256, 0, stream>>>(cnt, inv);
  k_cast_x<<<NN * KD / 4 / 256, 256, 0, stream>>>(x, xb);
  k_combine1<<<2304, 256, 0, stream>>>(bases1, comp1, root1, WT1);

  // layer 1: xall (cols 0..2047, bf16) + z1 = x@root1 + bias1 (cols 2048..2303)
  k_gemm<<<dim3(18, 235), 256, 0, stream>>>(xb, WT1, xall, z1, bias1, 2048, 256);
  k_scatter<<<EE, 256, 0, stream>>>(xall, ei, ety, inv, z1, 8);
  k_act<<<NN * KD / 4 / 256, 256, 0, stream>>>(z1, z1b);

  // layer 2
  k_combine2<<<1152, 256, 0, stream>>>(bases2, comp2, root2, WT2);
  k_gemm<<<dim3(9, 235), 256, 0, stream>>>(z1b, WT2, zall2, out, bias2, 1024, 128);
  k_scatter<<<EE / 2, 256, 0, stream>>>(zall2, ei, ety, inv, out, 7);
}

// Round 2
// 442.207 us; speedup vs baseline: 1.9676x; 1.9676x over previous
//
#include <hip/hip_runtime.h>
#include <hip/hip_bf16.h>
#include <stdint.h>

#define NN     30000
#define MPAD   30080          // 235 * 128
#define RR     8
#define NBASES 30
#define KD     256
#define EE     480000
#define NSEG   (NN * RR)

typedef unsigned short u16;
typedef __attribute__((ext_vector_type(8))) short bf16x8;   // 8 bf16 = 4 VGPRs
typedef __attribute__((ext_vector_type(4))) float f32x4;

__device__ __forceinline__ u16 f2b(float f) {
  union { float f; uint32_t u; } v; v.f = f;
  return (u16)((v.u + 0x7fffu + ((v.u >> 16) & 1u)) >> 16);   // RNE
}
__device__ __forceinline__ float b2f(u16 h) {
  union { uint32_t u; float f; } v; v.u = ((uint32_t)h) << 16;
  return v.f;
}

__device__ __forceinline__ void gl_lds16(const void* g, void* l) {
  __builtin_amdgcn_global_load_lds((__attribute__((address_space(1))) void*)g,
                                   (__attribute__((address_space(3))) void*)l,
                                   16, 0, 0);
}

// ---------------- bf16 MFMA GEMM: C[M x NC] = A[M x 256] * BT[NC x 256]^T ---
// cols < split  -> Cb (bf16, row width = split)
// cols >= split -> Cf (f32, row width = wf) + bias
__global__ void k_gemm(const u16* __restrict__ A, const u16* __restrict__ BT,
                       u16* __restrict__ Cb, float* __restrict__ Cf,
                       const float* __restrict__ bias, int split, int wf) {
  __shared__ u16 Alds[128 * 32];
  __shared__ u16 Blds[128 * 32];
  const int tid = threadIdx.x;
  const int w = tid >> 6, lane = tid & 63;
  const int bn = blockIdx.x * 128, bm = blockIdx.y * 128;
  const int wm = (w >> 1) * 64, wn = (w & 1) * 64;
  const int l15 = lane & 15, l4 = lane >> 4;

  f32x4 zero4 = {0.f, 0.f, 0.f, 0.f};
  f32x4 acc[4][4];
  #pragma unroll
  for (int mi = 0; mi < 4; ++mi)
    #pragma unroll
    for (int ni = 0; ni < 4; ++ni) acc[mi][ni] = zero4;

  for (int k0 = 0; k0 < KD; k0 += 32) {
    #pragma unroll
    for (int it = 0; it < 2; ++it) {
      int chb = it * 256 + w * 64;     // wave-uniform chunk base
      int ch = chb + lane;             // per-lane chunk (16B each)
      int row = ch >> 2, kq = (ch & 3) * 8;
      gl_lds16(&A[(size_t)(bm + row) * KD + k0 + kq], &Alds[(size_t)chb * 8]);
      gl_lds16(&BT[(size_t)(bn + row) * KD + k0 + kq], &Blds[(size_t)chb * 8]);
    }
    __syncthreads();
    bf16x8 av[4], bv[4];
    #pragma unroll
    for (int i = 0; i < 4; ++i) {
      av[i] = *(const bf16x8*)&Alds[(wm + i * 16 + l15) * 32 + l4 * 8];
      bv[i] = *(const bf16x8*)&Blds[(wn + i * 16 + l15) * 32 + l4 * 8];
    }
    #pragma unroll
    for (int mi = 0; mi < 4; ++mi)
      #pragma unroll
      for (int ni = 0; ni < 4; ++ni)
        acc[mi][ni] = __builtin_amdgcn_mfma_f32_16x16x32_bf16(av[mi], bv[ni], acc[mi][ni], 0, 0, 0);
    __syncthreads();
  }

  // epilogue: C/D layout col=lane&15, row=(lane>>4)*4+reg
  #pragma unroll
  for (int mi = 0; mi < 4; ++mi) {
    #pragma unroll
    for (int ni = 0; ni < 4; ++ni) {
      int col = bn + wn + ni * 16 + l15;
      #pragma unroll
      for (int v = 0; v < 4; ++v) {
        int row = bm + wm + mi * 16 + l4 * 4 + v;
        if (row < NN) {
          float val = acc[mi][ni][v];
          if (col < split) Cb[(size_t)row * split + col] = f2b(val);
          else             Cf[(size_t)row * wf + (col - split)] = val + bias[col - split];
        }
      }
    }
  }
}

// ---------------- small kernels ---------------------------------------------
__global__ void k_cast_x(const float* __restrict__ x, u16* __restrict__ xb) {
  int t = blockIdx.x * 256 + threadIdx.x;
  if (t < NN * KD / 4) {
    float4 v = ((const float4*)x)[t];
    union { u16 h[4]; uint2 u; } p;
    p.h[0] = f2b(v.x); p.h[1] = f2b(v.y); p.h[2] = f2b(v.z); p.h[3] = f2b(v.w);
    ((uint2*)xb)[t] = p.u;
  }
}

__global__ void k_combine1(const float* __restrict__ bases, const float* __restrict__ comp,
                           const float* __restrict__ root, u16* __restrict__ WT) {
  int t = blockIdx.x * 256 + threadIdx.x;          // 2304 blocks
  if (t < RR * 256 * 256) {
    int r = t >> 16, i = (t >> 8) & 255, o = t & 255;
    float acc = 0.f;
    #pragma unroll
    for (int b = 0; b < NBASES; ++b)
      acc += comp[r * NBASES + b] * bases[((size_t)b * 256 + i) * 256 + o];
    WT[((size_t)(r * 256 + o)) * KD + i] = f2b(acc);
  } else {
    int u = t - RR * 256 * 256;
    int i = u >> 8, o = u & 255;
    WT[((size_t)(2048 + o)) * KD + i] = f2b(root[i * 256 + o]);
  }
}

__global__ void k_combine2(const float* __restrict__ bases, const float* __restrict__ comp,
                           const float* __restrict__ root, u16* __restrict__ WT) {
  int t = blockIdx.x * 256 + threadIdx.x;          // 1152 blocks
  if (t < RR * 256 * 128) {
    int r = t >> 15, i = (t >> 7) & 255, o = t & 127;
    float acc = 0.f;
    #pragma unroll
    for (int b = 0; b < NBASES; ++b)
      acc += comp[r * NBASES + b] * bases[((size_t)b * 256 + i) * 128 + o];
    WT[((size_t)(r * 128 + o)) * KD + i] = f2b(acc);
  } else {
    int u = t - RR * 256 * 128;
    int i = u >> 7, o = u & 127;
    WT[((size_t)(1024 + o)) * KD + i] = f2b(root[i * 128 + o]);
  }
}

__global__ void k_hist(const int* __restrict__ ei, const int* __restrict__ ety,
                       int* __restrict__ cnt) {
  int e = blockIdx.x * 256 + threadIdx.x;
  if (e < EE) atomicAdd(&cnt[ei[EE + e] * RR + ety[e]], 1);
}

__global__ void k_inv(const int* __restrict__ cnt, float* __restrict__ inv) {
  int s = blockIdx.x * 256 + threadIdx.x;
  if (s < NSEG) { int c = cnt[s]; inv[s] = c > 0 ? 1.0f / (float)c : 0.f; }
}

// single-block scan: off[d+1] = sum_{d'<=d} deg(d'), deg = sum_r cnt[d*8+r]
// also zeroes cursor[]
__global__ void k_deg_scan(const int* __restrict__ cnt, int* __restrict__ off,
                           int* __restrict__ cursor) {
  __shared__ int lds[1024];
  __shared__ int carry;
  if (threadIdx.x == 0) { carry = 0; off[0] = 0; }
  __syncthreads();
  for (int base = 0; base < NN; base += 1024) {
    int i = base + (int)threadIdx.x;
    int deg = 0;
    if (i < NN) {
      #pragma unroll
      for (int r = 0; r < RR; ++r) deg += cnt[i * RR + r];
    }
    lds[threadIdx.x] = deg;
    __syncthreads();
    #pragma unroll
    for (int s = 1; s < 1024; s <<= 1) {
      int v = (threadIdx.x >= (unsigned)s) ? lds[threadIdx.x - s] : 0;
      __syncthreads();
      lds[threadIdx.x] += v;
      __syncthreads();
    }
    int incl = lds[threadIdx.x] + carry;
    if (i < NN) { off[i + 1] = incl; cursor[i] = 0; }
    __syncthreads();
    if (threadIdx.x == 1023) carry = incl;
    __syncthreads();
  }
}

// scatter edge payloads into CSR order (order within a dst is nondeterministic
// -> only perturbs fp rounding of the per-node sum)
__global__ void k_bucket(const int* __restrict__ ei, const int* __restrict__ ety,
                         const int* __restrict__ off, int* __restrict__ cursor,
                         int* __restrict__ srcrel) {
  int e = blockIdx.x * 256 + threadIdx.x;
  if (e < EE) {
    int d = ei[EE + e];
    int pos = off[d] + atomicAdd(&cursor[d], 1);
    srcrel[pos] = ei[e] * RR + ety[e];
  }
}

// one block per dst node: sum_{edges into d} xall[src,rel,:] * inv[d,rel],
// add zin (root+bias), optional leaky-relu + bf16 cast
template<int C, bool ACT>
__global__ void k_reduce(const u16* __restrict__ xall, const int* __restrict__ off,
                         const int* __restrict__ srcrel, const float* __restrict__ inv,
                         const float* __restrict__ zin, u16* __restrict__ zb_out,
                         float* __restrict__ f_out) {
  const int d = blockIdx.x;
  const int t = threadIdx.x;            // C/2 threads, 2 channels each
  float a0 = 0.f, a1 = 0.f;
  const int e1 = off[d + 1];
  for (int e = off[d]; e < e1; ++e) {
    int p = srcrel[e];                   // src*8 + rel (broadcast load)
    float w = inv[(d << 3) + (p & 7)];
    uint32_t pk = *(const uint32_t*)&xall[(size_t)p * C + 2 * t];
    a0 += b2f((u16)pk) * w;
    a1 += b2f((u16)(pk >> 16)) * w;
  }
  size_t o = (size_t)d * C + 2 * t;
  float2 z = *(const float2*)&zin[o];
  float z0 = z.x + a0, z1v = z.y + a1;
  if (ACT) {
    z0  = z0  > 0.f ? z0  : 0.01f * z0;
    z1v = z1v > 0.f ? z1v : 0.01f * z1v;
    uint32_t pk = ((uint32_t)f2b(z1v) << 16) | (uint32_t)f2b(z0);
    *(uint32_t*)&zb_out[o] = pk;
  } else {
    float2 zo; zo.x = z0; zo.y = z1v;
    *(float2*)&f_out[o] = zo;
  }
}

// ---------------- launch ----------------------------------------------------
extern "C" void kernel_launch(void* const* d_in, const int* in_sizes, int n_in,
                              void* d_out, int out_size, void* d_ws, size_t ws_size,
                              hipStream_t stream) {
  const float* x      = (const float*)d_in[0];
  const int*   ei     = (const int*)d_in[1];
  const int*   ety    = (const int*)d_in[2];
  const float* bases1 = (const float*)d_in[3];
  const float* comp1  = (const float*)d_in[4];
  const float* root1  = (const float*)d_in[5];
  const float* bias1  = (const float*)d_in[6];
  const float* bases2 = (const float*)d_in[7];
  const float* comp2  = (const float*)d_in[8];
  const float* root2  = (const float*)d_in[9];
  const float* bias2  = (const float*)d_in[10];
  float* out = (float*)d_out;

  char* p = (char*)d_ws;
  auto alloc = [&](size_t bytes) {
    char* q = p; p += (bytes + 255) & ~(size_t)255; return q;
  };
  u16*   xb     = (u16*)alloc((size_t)MPAD * KD * 2);
  u16*   WT1    = (u16*)alloc((size_t)2304 * KD * 2);
  u16*   xall   = (u16*)alloc((size_t)MPAD * 2048 * 2);  // reused as zall2
  float* z1     = (float*)alloc((size_t)NN * 256 * 4);
  u16*   z1b    = (u16*)alloc((size_t)MPAD * KD * 2);
  u16*   WT2    = (u16*)alloc((size_t)1152 * KD * 2);
  int*   cnt    = (int*)alloc((size_t)NSEG * 4);
  float* inv    = (float*)alloc((size_t)NSEG * 4);
  int*   off    = (int*)alloc((size_t)(NN + 1) * 4);
  int*   cursor = (int*)alloc((size_t)NN * 4);
  int*   srcrel = (int*)alloc((size_t)EE * 4);
  u16*   zall2  = xall;

  // CSR build
  hipMemsetAsync(cnt, 0, (size_t)NSEG * 4, stream);
  k_hist<<<(EE + 255) / 256, 256, 0, stream>>>(ei, ety, cnt);
  k_inv<<<(NSEG + 255) / 256, 256, 0, stream>>>(cnt, inv);
  k_deg_scan<<<1, 1024, 0, stream>>>(cnt, off, cursor);
  k_bucket<<<(EE + 255) / 256, 256, 0, stream>>>(ei, ety, off, cursor, srcrel);

  // layer 1
  k_cast_x<<<NN * KD / 4 / 256, 256, 0, stream>>>(x, xb);
  k_combine1<<<2304, 256, 0, stream>>>(bases1, comp1, root1, WT1);
  k_gemm<<<dim3(18, 235), 256, 0, stream>>>(xb, WT1, xall, z1, bias1, 2048, 256);
  k_reduce<256, true><<<NN, 128, 0, stream>>>(xall, off, srcrel, inv, z1, z1b, nullptr);

  // layer 2
  k_combine2<<<1152, 256, 0, stream>>>(bases2, comp2, root2, WT2);
  k_gemm<<<dim3(9, 235), 256, 0, stream>>>(z1b, WT2, zall2, out, bias2, 1024, 128);
  k_reduce<128, false><<<NN, 64, 0, stream>>>(zall2, off, srcrel, inv, out, nullptr, out);
}

// Round 4
// 420.053 us; speedup vs baseline: 2.0714x; 1.0527x over previous
//
#include <hip/hip_runtime.h>
#include <hip/hip_bf16.h>
#include <stdint.h>

#define NN     30000
#define MPAD   30080          // 470 * 64
#define RR     8
#define NBASES 30
#define KD     256
#define EE     480000
#define NSEG   (NN * RR)
#define K1     2048           // rel-chunk span of K (8 rels x 256)
#define KTOT   2304           // K1 + 256 root (both layers)

typedef unsigned short u16;
typedef __attribute__((ext_vector_type(8))) short bf16x8;   // 8 bf16 = 4 VGPRs
typedef __attribute__((ext_vector_type(4))) float f32x4;

__device__ __forceinline__ u16 f2b(float f) {
  union { float f; uint32_t u; } v; v.f = f;
  return (u16)((v.u + 0x7fffu + ((v.u >> 16) & 1u)) >> 16);   // RNE
}
__device__ __forceinline__ float b2f(u16 h) {
  union { uint32_t u; float f; } v; v.u = ((uint32_t)h) << 16;
  return v.f;
}

__device__ __forceinline__ void gl_lds16(const void* g, void* l) {
  __builtin_amdgcn_global_load_lds((__attribute__((address_space(1))) void*)g,
                                   (__attribute__((address_space(3))) void*)l,
                                   16, 0, 0);
}

// ------- GEMM: C[M x N] = [A1 | A2] @ BT^T, 64x128 tile, 2 waves ------------
// A1: [MPAD x 2048] bf16 (rel-means), A2: [MPAD x 256] bf16 (self term)
// BT: [N x KTOT] bf16 (K-major).  LAST=false: +bias, leaky, bf16 -> ob [MPAD x 256]
// LAST=true: +bias -> of [NN x 128] f32
template<bool LAST>
__global__ void k_gemm64(const u16* __restrict__ A1, const u16* __restrict__ A2,
                         const u16* __restrict__ BT, const float* __restrict__ bias,
                         u16* __restrict__ ob, float* __restrict__ of) {
  __shared__ u16 Alds[64 * 32];
  __shared__ u16 Blds[128 * 32];
  const int tid = threadIdx.x;          // 128 threads = 2 waves
  const int w = tid >> 6, lane = tid & 63;
  const int bn = blockIdx.x * 128, bm = blockIdx.y * 64;
  const int wn = w * 64;
  const int l15 = lane & 15, l4 = lane >> 4;

  f32x4 zero4 = {0.f, 0.f, 0.f, 0.f};
  f32x4 acc[4][4];
  #pragma unroll
  for (int mi = 0; mi < 4; ++mi)
    #pragma unroll
    for (int ni = 0; ni < 4; ++ni) acc[mi][ni] = zero4;

  for (int k0 = 0; k0 < KTOT; k0 += 32) {
    // A tile 64x32: 256 chunks of 16B; wave w stages [w*128, w*128+128)
    #pragma unroll
    for (int it = 0; it < 2; ++it) {
      int chb = w * 128 + it * 64;       // wave-uniform
      int ch = chb + lane;
      int row = ch >> 2, kq = (ch & 3) * 8;
      const u16* src = (k0 < K1)
          ? &A1[(size_t)(bm + row) * K1 + k0 + kq]
          : &A2[(size_t)(bm + row) * KD + (k0 - K1) + kq];
      gl_lds16(src, &Alds[(size_t)chb * 8]);
    }
    // B tile 128x32: 512 chunks; wave w stages [w*256, w*256+256)
    #pragma unroll
    for (int it = 0; it < 4; ++it) {
      int chb = w * 256 + it * 64;
      int ch = chb + lane;
      int row = ch >> 2, kq = (ch & 3) * 8;
      gl_lds16(&BT[(size_t)(bn + row) * KTOT + k0 + kq], &Blds[(size_t)chb * 8]);
    }
    __syncthreads();
    bf16x8 av[4], bv[4];
    #pragma unroll
    for (int i = 0; i < 4; ++i) {
      av[i] = *(const bf16x8*)&Alds[(i * 16 + l15) * 32 + l4 * 8];
      bv[i] = *(const bf16x8*)&Blds[(wn + i * 16 + l15) * 32 + l4 * 8];
    }
    #pragma unroll
    for (int mi = 0; mi < 4; ++mi)
      #pragma unroll
      for (int ni = 0; ni < 4; ++ni)
        acc[mi][ni] = __builtin_amdgcn_mfma_f32_16x16x32_bf16(av[mi], bv[ni], acc[mi][ni], 0, 0, 0);
    __syncthreads();
  }

  // epilogue: C/D layout col=lane&15, row=(lane>>4)*4+reg
  #pragma unroll
  for (int mi = 0; mi < 4; ++mi) {
    #pragma unroll
    for (int ni = 0; ni < 4; ++ni) {
      int col = bn + wn + ni * 16 + l15;
      float bb = bias[col];
      #pragma unroll
      for (int v = 0; v < 4; ++v) {
        int row = bm + mi * 16 + l4 * 4 + v;
        float val = acc[mi][ni][v] + bb;
        if (!LAST) {
          val = val > 0.f ? val : 0.01f * val;
          ob[(size_t)row * KD + col] = f2b(val);   // rows >= NN: finite garbage, ok
        } else if (row < NN) {
          of[(size_t)row * 128 + col] = val;
        }
      }
    }
  }
}

// ------- per-(dst,rel) mean of X rows -> H [d, r*256+c] --------------------
__global__ void k_mean(const u16* __restrict__ X, const int* __restrict__ off2,
                       const int* __restrict__ esrc, u16* __restrict__ H) {
  const int d = blockIdx.x;
  const int t = threadIdx.x;            // 128 threads, 2 channels each
  #pragma unroll 1
  for (int r = 0; r < RR; ++r) {
    int s = (d << 3) + r;
    int e0 = off2[s], e1 = off2[s + 1];
    float a0 = 0.f, a1 = 0.f;
    for (int e = e0; e < e1; ++e) {
      int src = esrc[e];
      uint32_t pk = *(const uint32_t*)&X[(size_t)src * KD + 2 * t];
      a0 += b2f((u16)pk);
      a1 += b2f((u16)(pk >> 16));
    }
    float sc = (e1 > e0) ? 1.f / (float)(e1 - e0) : 0.f;
    a0 *= sc; a1 *= sc;
    uint32_t pk = ((uint32_t)f2b(a1) << 16) | (uint32_t)f2b(a0);
    *(uint32_t*)&H[(size_t)d * K1 + (r << 8) + 2 * t] = pk;
  }
}

// ------- small kernels ------------------------------------------------------
__global__ void k_cast_x(const float* __restrict__ x, u16* __restrict__ xb) {
  int t = blockIdx.x * 256 + threadIdx.x;
  if (t < NN * KD / 4) {
    float4 v = ((const float4*)x)[t];
    union { u16 h[4]; uint2 u; } p;
    p.h[0] = f2b(v.x); p.h[1] = f2b(v.y); p.h[2] = f2b(v.z); p.h[3] = f2b(v.w);
    ((uint2*)xb)[t] = p.u;
  }
}

// BT1[o, k] for k<2048: sum_b comp1[r,b]*bases1[b,i,o]; k in [2048,2304): root1[i,o]
__global__ void k_combine1(const float* __restrict__ bases, const float* __restrict__ comp,
                           const float* __restrict__ root, u16* __restrict__ BT) {
  int k = blockIdx.x, o = threadIdx.x;   // 2304 blocks x 256 threads
  float v;
  if (k < K1) {
    int r = k >> 8, i = k & 255;
    float acc = 0.f;
    #pragma unroll
    for (int b = 0; b < NBASES; ++b)
      acc += comp[r * NBASES + b] * bases[(size_t)b * 65536 + i * 256 + o];
    v = acc;
  } else {
    v = root[(k - K1) * 256 + o];
  }
  BT[(size_t)o * KTOT + k] = f2b(v);
}

__global__ void k_combine2(const float* __restrict__ bases, const float* __restrict__ comp,
                           const float* __restrict__ root, u16* __restrict__ BT) {
  int k = blockIdx.x, o = threadIdx.x;   // 2304 blocks x 128 threads
  float v;
  if (k < K1) {
    int r = k >> 8, i = k & 255;
    float acc = 0.f;
    #pragma unroll
    for (int b = 0; b < NBASES; ++b)
      acc += comp[r * NBASES + b] * bases[(size_t)b * 32768 + i * 128 + o];
    v = acc;
  } else {
    v = root[(k - K1) * 128 + o];
  }
  BT[(size_t)o * KTOT + k] = f2b(v);
}

__global__ void k_hist(const int* __restrict__ ei, const int* __restrict__ ety,
                       int* __restrict__ cnt) {
  int e = blockIdx.x * 256 + threadIdx.x;
  if (e < EE) atomicAdd(&cnt[ei[EE + e] * RR + ety[e]], 1);
}

// hierarchical exclusive scan of cnt[NSEG] -> off2
__global__ void k_scan1(const int* __restrict__ cnt, int* __restrict__ off2,
                        int* __restrict__ bsum) {
  __shared__ int lds[1024];
  int i = blockIdx.x * 1024 + threadIdx.x;
  int v = (i < NSEG) ? cnt[i] : 0;
  lds[threadIdx.x] = v;
  __syncthreads();
  #pragma unroll
  for (int s = 1; s < 1024; s <<= 1) {
    int u = (threadIdx.x >= (unsigned)s) ? lds[threadIdx.x - s] : 0;
    __syncthreads();
    lds[threadIdx.x] += u;
    __syncthreads();
  }
  if (i < NSEG) off2[i] = lds[threadIdx.x] - v;        // exclusive within block
  if (threadIdx.x == 1023) bsum[blockIdx.x] = lds[1023];
}

__global__ void k_scan2(int* __restrict__ bsum, int* __restrict__ boff, int nb) {
  __shared__ int lds[256];
  int v = (threadIdx.x < (unsigned)nb) ? bsum[threadIdx.x] : 0;
  lds[threadIdx.x] = v;
  __syncthreads();
  #pragma unroll
  for (int s = 1; s < 256; s <<= 1) {
    int u = (threadIdx.x >= (unsigned)s) ? lds[threadIdx.x - s] : 0;
    __syncthreads();
    lds[threadIdx.x] += u;
    __syncthreads();
  }
  if (threadIdx.x < (unsigned)nb) boff[threadIdx.x] = lds[threadIdx.x] - v;
}

__global__ void k_scan3(int* __restrict__ off2, const int* __restrict__ boff,
                        int* __restrict__ cursor) {
  int i = blockIdx.x * 1024 + threadIdx.x;
  if (i < NSEG) {
    off2[i] += boff[blockIdx.x];
    cursor[i] = 0;
  }
  if (i == 0) off2[NSEG] = EE;
}

__global__ void k_bucket(const int* __restrict__ ei, const int* __restrict__ ety,
                         const int* __restrict__ off2, int* __restrict__ cursor,
                         int* __restrict__ esrc) {
  int e = blockIdx.x * 256 + threadIdx.x;
  if (e < EE) {
    int seg = ei[EE + e] * RR + ety[e];
    int pos = off2[seg] + atomicAdd(&cursor[seg], 1);
    esrc[pos] = ei[e];
  }
}

// ------- launch -------------------------------------------------------------
extern "C" void kernel_launch(void* const* d_in, const int* in_sizes, int n_in,
                              void* d_out, int out_size, void* d_ws, size_t ws_size,
                              hipStream_t stream) {
  const float* x      = (const float*)d_in[0];
  const int*   ei     = (const int*)d_in[1];
  const int*   ety    = (const int*)d_in[2];
  const float* bases1 = (const float*)d_in[3];
  const float* comp1  = (const float*)d_in[4];
  const float* root1  = (const float*)d_in[5];
  const float* bias1  = (const float*)d_in[6];
  const float* bases2 = (const float*)d_in[7];
  const float* comp2  = (const float*)d_in[8];
  const float* root2  = (const float*)d_in[9];
  const float* bias2  = (const float*)d_in[10];
  float* out = (float*)d_out;

  char* p = (char*)d_ws;
  auto alloc = [&](size_t bytes) {
    char* q = p; p += (bytes + 255) & ~(size_t)255; return q;
  };
  u16* H      = (u16*)alloc((size_t)MPAD * K1 * 2);    // 123 MB, reused by layer 2
  u16* xb     = (u16*)alloc((size_t)MPAD * KD * 2);    // 15 MB
  u16* z1b    = (u16*)alloc((size_t)MPAD * KD * 2);    // 15 MB
  u16* BT1    = (u16*)alloc((size_t)256 * KTOT * 2);
  u16* BT2    = (u16*)alloc((size_t)128 * KTOT * 2);
  int* cnt    = (int*)alloc((size_t)NSEG * 4);
  int* off2   = (int*)alloc((size_t)(NSEG + 1) * 4);
  int* cursor = (int*)alloc((size_t)NSEG * 4);
  int* esrc   = (int*)alloc((size_t)EE * 4);
  int* bsum   = (int*)alloc((size_t)256 * 4);
  int* boff   = (int*)alloc((size_t)256 * 4);

  const int NB = (NSEG + 1023) / 1024;                 // 235

  // CSR by (dst,rel) segment
  hipMemsetAsync(cnt, 0, (size_t)NSEG * 4, stream);
  k_hist<<<(EE + 255) / 256, 256, 0, stream>>>(ei, ety, cnt);
  k_scan1<<<NB, 1024, 0, stream>>>(cnt, off2, bsum);
  k_scan2<<<1, 256, 0, stream>>>(bsum, boff, NB);
  k_scan3<<<NB, 1024, 0, stream>>>(off2, boff, cursor);
  k_bucket<<<(EE + 255) / 256, 256, 0, stream>>>(ei, ety, off2, cursor, esrc);

  // weights + input cast
  k_cast_x<<<NN * KD / 4 / 256, 256, 0, stream>>>(x, xb);
  k_combine1<<<KTOT, 256, 0, stream>>>(bases1, comp1, root1, BT1);
  k_combine2<<<KTOT, 128, 0, stream>>>(bases2, comp2, root2, BT2);

  // layer 1: H = per-(d,r) mean of xb; z1b = leaky([H|xb] @ BT1^T + bias1)
  k_mean<<<NN, 128, 0, stream>>>(xb, off2, esrc, H);
  k_gemm64<false><<<dim3(2, 470), 128, 0, stream>>>(H, xb, BT1, bias1, z1b, nullptr);

  // layer 2: H = per-(d,r) mean of z1b; out = [H|z1b] @ BT2^T + bias2
  k_mean<<<NN, 128, 0, stream>>>(z1b, off2, esrc, H);
  k_gemm64<true><<<dim3(1, 470), 128, 0, stream>>>(H, z1b, BT2, bias2, nullptr, out);
}